// Round 5
// baseline (1195.538 us; speedup 1.0000x reference)
//
#include <hip/hip_runtime.h>
#include <hip/hip_bf16.h>

#define BB 8
#define SS 512
#define DD 1024
#define HH 16
#define DHH 64
#define FFF 4096
#define MM (BB*SS)        // 4096
#define HD (HH*DHH)       // 1024
#define CD ((HH+1)*DHH)   // 1088
#define QKV_LD 3072

#define NEG_MIN (-3.4028234663852886e38f)
#define FLT_MAX_ (3.402823466e+38f)

typedef __attribute__((ext_vector_type(8)))  __bf16 bf16x8;
typedef __attribute__((ext_vector_type(16))) float  f32x16;

__device__ __forceinline__ unsigned short bf16_rne(float x) {
    unsigned int u = __float_as_uint(x);
    u += 0x7FFFu + ((u >> 16) & 1u);
    return (unsigned short)(u >> 16);
}
__device__ __forceinline__ float bf16f(unsigned short h) {
    return __uint_as_float(((unsigned int)h) << 16);
}
__device__ __forceinline__ void split2(float x, unsigned short& h, unsigned short& l) {
    h = bf16_rne(x);
    l = bf16_rne(x - bf16f(h));
}

// ------------------------------------------------- LayerNorm -> hi/lo planes
__global__ __launch_bounds__(256)
void ln_plane_kernel(const float* __restrict__ x, const float* __restrict__ g,
                     const float* __restrict__ bta,
                     unsigned short* __restrict__ oh, unsigned short* __restrict__ ol)
{
    const int row = blockIdx.x;
    const int tid = threadIdx.x;
    const float* xr = x + (size_t)row * DD;
    float4 xv = *(const float4*)(xr + tid * 4);
    float s  = xv.x + xv.y + xv.z + xv.w;
    float ss = xv.x*xv.x + xv.y*xv.y + xv.z*xv.z + xv.w*xv.w;
    #pragma unroll
    for (int off = 32; off > 0; off >>= 1) {
        s  += __shfl_down(s, off);
        ss += __shfl_down(ss, off);
    }
    __shared__ float red[8];
    const int wid = tid >> 6;
    if ((tid & 63) == 0) { red[wid*2] = s; red[wid*2+1] = ss; }
    __syncthreads();
    s  = red[0] + red[2] + red[4] + red[6];
    ss = red[1] + red[3] + red[5] + red[7];
    const float mu  = s * (1.0f / DD);
    const float var = ss * (1.0f / DD) - mu * mu;
    const float inv = 1.0f / sqrtf(var + 1e-6f);
    float4 gv = *(const float4*)(g + tid*4);
    float4 bv = *(const float4*)(bta + tid*4);
    float o0 = (xv.x - mu) * inv * gv.x + bv.x;
    float o1 = (xv.y - mu) * inv * gv.y + bv.y;
    float o2 = (xv.z - mu) * inv * gv.z + bv.z;
    float o3 = (xv.w - mu) * inv * gv.w + bv.w;
    ushort4 h4, l4;
    split2(o0, h4.x, l4.x); split2(o1, h4.y, l4.y);
    split2(o2, h4.z, l4.z); split2(o3, h4.w, l4.w);
    *(ushort4*)&oh[(size_t)row * DD + tid*4] = h4;
    *(ushort4*)&ol[(size_t)row * DD + tid*4] = l4;
}

// ---------------------------------------------------------------- MFMA GEMM
// C = epi( (Ahi+Alo)[M,K] @ B[K,N](fp32) + bias ), split-bf16 (3 MFMA).
// A comes pre-split as bf16 hi/lo planes (producer-fused conversion).
// 128xNT tile, BK=32, 256 thr = 4 waves (2x2). Register prefetch (T14):
// next tile's global loads issue right after the staging barrier.
// LDS packed in fragment order: all LDS ops bank-balanced, frag reads are
// base + lane*16B.
template<bool QKV, bool HAS_RES, bool LEAKY, bool OUTP, int NT>
__global__ __launch_bounds__(256, 3)
void gemm_mfma(const unsigned short* __restrict__ Ahi,
               const unsigned short* __restrict__ Alo,
               const float* __restrict__ B0, const float* __restrict__ B1,
               const float* __restrict__ B2,
               const float* __restrict__ bias0, const float* __restrict__ bias1,
               const float* __restrict__ bias2,
               const float* __restrict__ res, float* __restrict__ Cf,
               unsigned short* __restrict__ Chi, unsigned short* __restrict__ Clo,
               int K, int lda, int ldb, int ldc)
{
    static_assert(NT == 64 || NT == 128, "");
    constexpr int NF    = NT / 64;    // per-wave N frags
    constexpr int BFRAG = NT / 32;    // B frags per ks
    constexpr int KG    = 256 / NT;   // k-groups in B staging
    constexpr int KPT   = 32 / KG;    // k per thread in B staging

    __shared__ unsigned short Ah[4096];
    __shared__ unsigned short Al[4096];
    __shared__ unsigned short Bh[BFRAG * 2 * 64 * 8];
    __shared__ unsigned short Bl[BFRAG * 2 * 64 * 8];

    const int tid = threadIdx.x;
    const int bm  = blockIdx.y;
    int bn = blockIdx.x;

    const float* Bw   = B0;
    const float* bias = bias0;
    float scale = 1.0f;
    if (QKV) {
        const int sel = bn >> 3;          // 0:q 1:k 2:v (each 1024 cols, NT=128)
        Bw   = (sel == 0) ? B0 : (sel == 1 ? B1 : B2);
        bias = (sel == 0) ? bias0 : (sel == 1 ? bias1 : bias2);
        scale = (sel == 0) ? 0.125f : 1.0f;
        bn &= 7;
    }

    const int wid  = tid >> 6, lane = tid & 63;
    const int wr   = wid >> 1, wc = wid & 1;
    const int lr   = lane & 31, kb = lane >> 5;

    f32x16 acc[2][NF];
    #pragma unroll
    for (int i = 0; i < 2; i++)
        #pragma unroll
        for (int j = 0; j < NF; j++)
            #pragma unroll
            for (int r = 0; r < 16; r++) acc[i][j][r] = 0.f;

    // A staging ownership: thread -> (row ar, octets ao..ao+1)
    const int ar = tid >> 1, ao = (tid & 1) * 2;
    const unsigned short* Ahp = Ahi + (size_t)(bm*128 + ar) * lda + ao*8;
    const unsigned short* Alp = Alo + (size_t)(bm*128 + ar) * lda + ao*8;
    // B staging ownership
    const int nn = tid % NT, kg = tid / NT;
    const float* Bptr = Bw + (size_t)(kg*KPT) * ldb + bn*NT + nn;

    uint4 apfh[2], apfl[2];
    float bpf[KPT];

    auto load_tiles = [&](int koff) {
        apfh[0] = *(const uint4*)(Ahp + koff);
        apfh[1] = *(const uint4*)(Ahp + koff + 8);
        apfl[0] = *(const uint4*)(Alp + koff);
        apfl[1] = *(const uint4*)(Alp + koff + 8);
        #pragma unroll
        for (int j = 0; j < KPT; ++j)
            bpf[j] = Bptr[(size_t)(koff + j) * ldb];
    };
    auto stage_tiles = [&]() {
        #pragma unroll
        for (int c = 0; c < 2; ++c) {
            const int o = ao + c, ks = o >> 1, khf = o & 1;
            const int idx = ((ks*4 + (ar>>5))*64 + (ar & 31) + 32*khf) * 8;
            *(uint4*)&Ah[idx] = apfh[c];
            *(uint4*)&Al[idx] = apfl[c];
        }
        #pragma unroll
        for (int c = 0; c < KPT/8; ++c) {
            unsigned int hw[4], lw[4];
            #pragma unroll
            for (int p = 0; p < 4; ++p) {
                unsigned short h0, l0, h1, l1;
                split2(bpf[c*8 + 2*p],     h0, l0);
                split2(bpf[c*8 + 2*p + 1], h1, l1);
                hw[p] = (unsigned int)h0 | ((unsigned int)h1 << 16);
                lw[p] = (unsigned int)l0 | ((unsigned int)l1 << 16);
            }
            const int k    = kg*KPT + c*8;
            const int base = (((k>>4)*BFRAG + (nn>>5))*64 + (nn & 31) + 32*((k>>3)&1))*8;
            *(uint4*)&Bh[base] = make_uint4(hw[0], hw[1], hw[2], hw[3]);
            *(uint4*)&Bl[base] = make_uint4(lw[0], lw[1], lw[2], lw[3]);
        }
    };

    load_tiles(0);

    for (int k0 = 0; k0 < K; k0 += 32) {
        stage_tiles();                    // waits on prefetch regs (data-dep)
        __syncthreads();                  // staging visible
        if (k0 + 32 < K) load_tiles(k0 + 32);  // issue-early; MFMA hides latency

        #pragma unroll
        for (int ks = 0; ks < 2; ++ks) {
            bf16x8 ah[2], al2[2], bh2[NF], bl2[NF];
            #pragma unroll
            for (int mf = 0; mf < 2; ++mf) {
                const int idx = ((ks*4 + wr*2 + mf)*64 + lane) * 8;
                ah[mf]  = *(const bf16x8*)&Ah[idx];
                al2[mf] = *(const bf16x8*)&Al[idx];
            }
            #pragma unroll
            for (int nf = 0; nf < NF; ++nf) {
                const int idx = ((ks*BFRAG + wc*NF + nf)*64 + lane) * 8;
                bh2[nf] = *(const bf16x8*)&Bh[idx];
                bl2[nf] = *(const bf16x8*)&Bl[idx];
            }
            __builtin_amdgcn_s_setprio(1);
            #pragma unroll
            for (int mf = 0; mf < 2; ++mf)
                #pragma unroll
                for (int nf = 0; nf < NF; ++nf) {
                    acc[mf][nf] = __builtin_amdgcn_mfma_f32_32x32x16_bf16(ah[mf],  bh2[nf], acc[mf][nf], 0, 0, 0);
                    acc[mf][nf] = __builtin_amdgcn_mfma_f32_32x32x16_bf16(ah[mf],  bl2[nf], acc[mf][nf], 0, 0, 0);
                    acc[mf][nf] = __builtin_amdgcn_mfma_f32_32x32x16_bf16(al2[mf], bh2[nf], acc[mf][nf], 0, 0, 0);
                }
            __builtin_amdgcn_s_setprio(0);
        }
        __syncthreads();                  // LDS reads done before next staging
    }

    // ---- epilogue. C/D layout: col=lane&31, row=4*(lane>>5)+(r&3)+8*(r>>2)
    #pragma unroll
    for (int mf = 0; mf < 2; ++mf)
        #pragma unroll
        for (int nf = 0; nf < NF; ++nf) {
            const int gcol = blockIdx.x*NT + wc*(32*NF) + nf*32 + lr;
            const float bsv = bias[bn*NT + wc*(32*NF) + nf*32 + lr];
            #pragma unroll
            for (int r = 0; r < 16; ++r) {
                const int grow = bm*128 + wr*64 + mf*32 + kb*4 + (r & 3) + 8*(r >> 2);
                float o = (acc[mf][nf][r] + bsv) * scale;
                if (HAS_RES) o += res[(size_t)grow * ldc + gcol];
                if (LEAKY)   o = o > 0.f ? o : 0.2f * o;
                if (OUTP) {
                    unsigned short h, l;
                    split2(o, h, l);
                    Chi[(size_t)grow * ldc + gcol] = h;
                    Clo[(size_t)grow * ldc + gcol] = l;
                } else {
                    Cf[(size_t)grow * ldc + gcol] = o;
                }
            }
        }
}

// ---------------------------------------------------------------- Attention
// grid (S/64, H+1, B); 256 threads. Flash-style over 8 key tiles of 64.
// q/k/v in fused qkv buffer [M][3072]. Output written as bf16 hi/lo planes.
__global__ __launch_bounds__(256)
void attn_kernel(const float* __restrict__ qkv, const float* __restrict__ mask,
                 const float* __restrict__ sattn, const float* __restrict__ sval,
                 unsigned short* __restrict__ combh, unsigned short* __restrict__ combl)
{
    __shared__ float QsT[64][64];   // [d][i]
    __shared__ float KT [64][64];   // [d][j]  (reused as PsT[j][i])
    __shared__ float Vs [64][64];   // [j][d]
    const int tid = threadIdx.x;
    const int tx = tid & 15, ty = tid >> 4;
    const int qt = blockIdx.x, hh = blockIdx.y, b = blockIdx.z;
    const bool special = (hh == HH);

    const int li  = tid >> 2;          // 0..63
    const int ld0 = (tid & 3) * 16;    // 0,16,32,48

    if (!special) {
        const float* qbase = qkv + ((size_t)(b*SS + qt*64 + li)) * QKV_LD + hh*DHH;
        #pragma unroll
        for (int u = 0; u < 4; u++) {
            float4 t = *(const float4*)(qbase + ld0 + u*4);
            QsT[ld0+u*4+0][li] = t.x; QsT[ld0+u*4+1][li] = t.y;
            QsT[ld0+u*4+2][li] = t.z; QsT[ld0+u*4+3][li] = t.w;
        }
    }

    float m_i[4], l_i[4], oacc[4][4];
    #pragma unroll
    for (int r = 0; r < 4; r++) {
        m_i[r] = -FLT_MAX_;
        l_i[r] = special ? 1.f : 0.f;
        #pragma unroll
        for (int c = 0; c < 4; c++) oacc[r][c] = 0.f;
    }

    for (int kt = 0; kt < 8; ++kt) {
        __syncthreads();   // previous PV reads done
        if (!special) {
            const float* kbase = qkv + ((size_t)(b*SS + kt*64 + li)) * QKV_LD + HD + hh*DHH;
            #pragma unroll
            for (int u = 0; u < 4; u++) {
                float4 t = *(const float4*)(kbase + ld0 + u*4);
                KT[ld0+u*4+0][li] = t.x; KT[ld0+u*4+1][li] = t.y;
                KT[ld0+u*4+2][li] = t.z; KT[ld0+u*4+3][li] = t.w;
            }
        } else {
            const float* pbase = sattn + ((size_t)b*SS + qt*64 + li) * SS + kt*64;
            #pragma unroll
            for (int u = 0; u < 4; u++) {
                float4 t = *(const float4*)(pbase + ld0 + u*4);
                KT[ld0+u*4+0][li] = t.x; KT[ld0+u*4+1][li] = t.y;
                KT[ld0+u*4+2][li] = t.z; KT[ld0+u*4+3][li] = t.w;
            }
        }
        {
            const float* vbase = (hh == 0)
                ? (sval + ((size_t)b*SS + kt*64 + li) * DHH)
                : (qkv + ((size_t)(b*SS + kt*64 + li)) * QKV_LD + 2*HD + (hh-1)*DHH);
            #pragma unroll
            for (int u = 0; u < 4; u++) {
                float4 t = *(const float4*)(vbase + ld0 + u*4);
                *(float4*)&Vs[li][ld0 + u*4] = t;
            }
        }
        __syncthreads();

        if (!special) {
            float sc[4][4];
            #pragma unroll
            for (int r = 0; r < 4; r++)
                #pragma unroll
                for (int c = 0; c < 4; c++) sc[r][c] = 0.f;
            #pragma unroll 8
            for (int d = 0; d < 64; ++d) {
                float4 qa = *(const float4*)&QsT[d][ty*4];
                float4 kb = *(const float4*)&KT[d][tx*4];
                float av[4] = {qa.x, qa.y, qa.z, qa.w};
                float bv[4] = {kb.x, kb.y, kb.z, kb.w};
                #pragma unroll
                for (int r = 0; r < 4; r++)
                    #pragma unroll
                    for (int c = 0; c < 4; c++)
                        sc[r][c] = fmaf(av[r], bv[c], sc[r][c]);
            }
            #pragma unroll
            for (int c = 0; c < 4; c++) {
                const float mk = mask[b*SS + kt*64 + tx*4 + c];
                const float add = (1.0f - mk) * NEG_MIN;
                #pragma unroll
                for (int r = 0; r < 4; r++)
                    sc[r][c] = sc[r][c] * mk + add;
            }
            float p[4][4];
            #pragma unroll
            for (int r = 0; r < 4; r++) {
                float rm = fmaxf(fmaxf(sc[r][0], sc[r][1]), fmaxf(sc[r][2], sc[r][3]));
                #pragma unroll
                for (int off = 1; off < 16; off <<= 1)
                    rm = fmaxf(rm, __shfl_xor(rm, off));
                const float m_new = fmaxf(m_i[r], rm);
                const float corr  = __expf(m_i[r] - m_new);
                float rs = 0.f;
                #pragma unroll
                for (int c = 0; c < 4; c++) {
                    p[r][c] = __expf(sc[r][c] - m_new);
                    rs += p[r][c];
                }
                #pragma unroll
                for (int off = 1; off < 16; off <<= 1)
                    rs += __shfl_xor(rs, off);
                l_i[r] = l_i[r] * corr + rs;
                m_i[r] = m_new;
                #pragma unroll
                for (int c = 0; c < 4; c++) oacc[r][c] *= corr;
            }
            __syncthreads();   // done reading KT
            #pragma unroll
            for (int r = 0; r < 4; r++)
                #pragma unroll
                for (int c = 0; c < 4; c++)
                    KT[tx*4+c][ty*4+r] = p[r][c];   // PsT[j][i]
            __syncthreads();   // PsT ready
        }
        #pragma unroll 8
        for (int j = 0; j < 64; ++j) {
            float4 pa = *(const float4*)&KT[j][ty*4];
            float4 vb = *(const float4*)&Vs[j][tx*4];
            float av[4] = {pa.x, pa.y, pa.z, pa.w};
            float bv[4] = {vb.x, vb.y, vb.z, vb.w};
            #pragma unroll
            for (int r = 0; r < 4; r++)
                #pragma unroll
                for (int c = 0; c < 4; c++)
                    oacc[r][c] = fmaf(av[r], bv[c], oacc[r][c]);
        }
    }
    #pragma unroll
    for (int r = 0; r < 4; r++) {
        const size_t row = (size_t)(b*SS + qt*64 + ty*4 + r);
        const float invl = 1.0f / l_i[r];
        ushort4 h4, l4;
        split2(oacc[r][0]*invl, h4.x, l4.x);
        split2(oacc[r][1]*invl, h4.y, l4.y);
        split2(oacc[r][2]*invl, h4.z, l4.z);
        split2(oacc[r][3]*invl, h4.w, l4.w);
        *(ushort4*)&combh[row * CD + hh*DHH + tx*4] = h4;
        *(ushort4*)&combl[row * CD + hh*DHH + tx*4] = l4;
    }
}

// ---------------------------------------------------------------- launch
extern "C" void kernel_launch(void* const* d_in, const int* in_sizes, int n_in,
                              void* d_out, int out_size, void* d_ws, size_t ws_size,
                              hipStream_t stream)
{
    const float* x     = (const float*)d_in[0];
    const float* mask  = (const float*)d_in[1];
    const float* sattn = (const float*)d_in[2];
    const float* sval  = (const float*)d_in[3];
    const float* Wq    = (const float*)d_in[4];
    const float* bq    = (const float*)d_in[5];
    const float* Wk    = (const float*)d_in[6];
    const float* bk    = (const float*)d_in[7];
    const float* Wv    = (const float*)d_in[8];
    const float* bv    = (const float*)d_in[9];
    const float* Wo    = (const float*)d_in[10];
    const float* bo    = (const float*)d_in[11];
    const float* ln1g  = (const float*)d_in[12];
    const float* ln1b  = (const float*)d_in[13];
    const float* W1    = (const float*)d_in[14];
    const float* b1    = (const float*)d_in[15];
    const float* W2    = (const float*)d_in[16];
    const float* b2    = (const float*)d_in[17];
    const float* ln2g  = (const float*)d_in[18];
    const float* ln2b  = (const float*)d_in[19];

    // ws layout (bytes) — identical 118,489,088-byte extent to the validated run.
    char* wsb = (char*)d_ws;
    unsigned short* yh    = (unsigned short*)(wsb);               //  8,388,608
    unsigned short* yl    = (unsigned short*)(wsb + 8388608);     //  8,388,608
    float*          qkv   = (float*)         (wsb + 16777216);    // 50,331,648
    unsigned short* hhp   = (unsigned short*)(wsb);               // 33,554,432 (aliases y+qkv, dead)
    unsigned short* hlp   = (unsigned short*)(wsb + 33554432);    // 33,554,432 (ends 67,108,864)
    unsigned short* combh = (unsigned short*)(wsb + 67108864);    //  8,912,896
    unsigned short* combl = (unsigned short*)(wsb + 76021760);    //  8,912,896
    float*          x2    = (float*)         (wsb + 84934656);    // 16,777,216
    unsigned short* y2h   = (unsigned short*)(wsb + 101711872);   //  8,388,608
    unsigned short* y2l   = (unsigned short*)(wsb + 110100480);   //  8,388,608

    const dim3 blk(256);

    ln_plane_kernel<<<MM, blk, 0, stream>>>(x, ln1g, ln1b, yh, yl);

    gemm_mfma<true,false,false,false,128><<<dim3(24, 32), blk, 0, stream>>>(
        yh, yl, Wq, Wk, Wv, bq, bk, bv,
        nullptr, qkv, nullptr, nullptr, DD, DD, DD, QKV_LD);

    attn_kernel<<<dim3(SS/64, HH+1, BB), blk, 0, stream>>>(qkv, mask, sattn, sval, combh, combl);

    gemm_mfma<false,true,false,false,64><<<dim3(16, 32), blk, 0, stream>>>(
        combh, combl, Wo, nullptr, nullptr, bo, nullptr, nullptr,
        x, x2, nullptr, nullptr, CD, CD, DD, DD);

    ln_plane_kernel<<<MM, blk, 0, stream>>>(x2, ln2g, ln2b, y2h, y2l);

    gemm_mfma<false,false,true,true,128><<<dim3(32, 32), blk, 0, stream>>>(
        y2h, y2l, W1, nullptr, nullptr, b1, nullptr, nullptr,
        nullptr, nullptr, hhp, hlp, DD, DD, FFF, FFF);

    gemm_mfma<false,true,false,false,64><<<dim3(16, 32), blk, 0, stream>>>(
        hhp, hlp, W2, nullptr, nullptr, b2, nullptr, nullptr,
        x2, (float*)d_out, nullptr, nullptr, FFF, FFF, DD, DD);
}

// Round 7
// 752.996 us; speedup vs baseline: 1.5877x; 1.5877x over previous
//
#include <hip/hip_runtime.h>
#include <hip/hip_bf16.h>

#define BB 8
#define SS 512
#define DD 1024
#define HH 16
#define DHH 64
#define FFF 4096
#define MM (BB*SS)        // 4096
#define HD (HH*DHH)       // 1024
#define CD ((HH+1)*DHH)   // 1088
#define QKV_LD 3072

#define NEG_MIN (-3.4028234663852886e38f)
#define FLT_MAX_ (3.402823466e+38f)

typedef __attribute__((ext_vector_type(8)))  __bf16 bf16x8;
typedef __attribute__((ext_vector_type(16))) float  f32x16;

__device__ __forceinline__ unsigned short bf16_rne(float x) {
    unsigned int u = __float_as_uint(x);
    u += 0x7FFFu + ((u >> 16) & 1u);
    return (unsigned short)(u >> 16);
}
__device__ __forceinline__ float bf16f(unsigned short h) {
    return __uint_as_float(((unsigned int)h) << 16);
}
__device__ __forceinline__ void split2(float x, unsigned short& h, unsigned short& l) {
    h = bf16_rne(x);
    l = bf16_rne(x - bf16f(h));
}

// ------------------------------------------------- LayerNorm -> hi/lo planes
__global__ __launch_bounds__(256)
void ln_plane_kernel(const float* __restrict__ x, const float* __restrict__ g,
                     const float* __restrict__ bta,
                     unsigned short* __restrict__ oh, unsigned short* __restrict__ ol)
{
    const int row = blockIdx.x;
    const int tid = threadIdx.x;
    const float* xr = x + (size_t)row * DD;
    float4 xv = *(const float4*)(xr + tid * 4);
    float s  = xv.x + xv.y + xv.z + xv.w;
    float ss = xv.x*xv.x + xv.y*xv.y + xv.z*xv.z + xv.w*xv.w;
    #pragma unroll
    for (int off = 32; off > 0; off >>= 1) {
        s  += __shfl_down(s, off);
        ss += __shfl_down(ss, off);
    }
    __shared__ float red[8];
    const int wid = tid >> 6;
    if ((tid & 63) == 0) { red[wid*2] = s; red[wid*2+1] = ss; }
    __syncthreads();
    s  = red[0] + red[2] + red[4] + red[6];
    ss = red[1] + red[3] + red[5] + red[7];
    const float mu  = s * (1.0f / DD);
    const float var = ss * (1.0f / DD) - mu * mu;
    const float inv = 1.0f / sqrtf(var + 1e-6f);
    float4 gv = *(const float4*)(g + tid*4);
    float4 bv = *(const float4*)(bta + tid*4);
    float o0 = (xv.x - mu) * inv * gv.x + bv.x;
    float o1 = (xv.y - mu) * inv * gv.y + bv.y;
    float o2 = (xv.z - mu) * inv * gv.z + bv.z;
    float o3 = (xv.w - mu) * inv * gv.w + bv.w;
    ushort4 h4, l4;
    split2(o0, h4.x, l4.x); split2(o1, h4.y, l4.y);
    split2(o2, h4.z, l4.z); split2(o3, h4.w, l4.w);
    *(ushort4*)&oh[(size_t)row * DD + tid*4] = h4;
    *(ushort4*)&ol[(size_t)row * DD + tid*4] = l4;
}

// ---------------------------------------------------------------- MFMA GEMM
// C = epi( (Ahi+Alo)[M,K] @ B[K,N](fp32) + bias ), split-bf16 (3 MFMA).
// A pre-split as bf16 hi/lo planes. 128xNT tile, BK=32, 256 thr = 4 waves.
// Register prefetch written INLINE (no lambdas), loads UNCONDITIONAL
// (k wraps to 0 on the last iteration) so the prefetch state stays in
// registers (no scratch). LDS packed in fragment order: frag reads are
// base + lane*16B, all staging bank-balanced.
template<bool QKV, bool HAS_RES, bool LEAKY, bool OUTP, int NT>
__global__ __launch_bounds__(256)
void gemm_mfma(const unsigned short* __restrict__ Ahi,
               const unsigned short* __restrict__ Alo,
               const float* __restrict__ B0, const float* __restrict__ B1,
               const float* __restrict__ B2,
               const float* __restrict__ bias0, const float* __restrict__ bias1,
               const float* __restrict__ bias2,
               const float* __restrict__ res, float* __restrict__ Cf,
               unsigned short* __restrict__ Chi, unsigned short* __restrict__ Clo,
               int K, int lda, int ldb, int ldc)
{
    static_assert(NT == 64 || NT == 128, "");
    constexpr int NF    = NT / 64;    // per-wave N frags
    constexpr int BFRAG = NT / 32;    // B frags per ks
    constexpr int KG    = 256 / NT;   // k-groups in B staging
    constexpr int KPT   = 32 / KG;    // k per thread in B staging

    __shared__ unsigned short Ah[4096];
    __shared__ unsigned short Al[4096];
    __shared__ unsigned short Bh[BFRAG * 2 * 64 * 8];
    __shared__ unsigned short Bl[BFRAG * 2 * 64 * 8];

    const int tid = threadIdx.x;
    const int bm  = blockIdx.y;
    int bn = blockIdx.x;

    const float* Bw   = B0;
    const float* bias = bias0;
    float scale = 1.0f;
    if (QKV) {
        const int sel = bn >> 3;          // 0:q 1:k 2:v (each 1024 cols, NT=128)
        Bw   = (sel == 0) ? B0 : (sel == 1 ? B1 : B2);
        bias = (sel == 0) ? bias0 : (sel == 1 ? bias1 : bias2);
        scale = (sel == 0) ? 0.125f : 1.0f;
        bn &= 7;
    }

    const int wid  = tid >> 6, lane = tid & 63;
    const int wr   = wid >> 1, wc = wid & 1;
    const int lr   = lane & 31, kb = lane >> 5;

    f32x16 acc[2][NF];
    #pragma unroll
    for (int i = 0; i < 2; i++)
        #pragma unroll
        for (int j = 0; j < NF; j++)
            #pragma unroll
            for (int r = 0; r < 16; r++) acc[i][j][r] = 0.f;

    // A staging ownership: thread -> (row ar, octets ao, ao+1)
    const int ar = tid >> 1, ao = (tid & 1) * 2;
    const unsigned short* Ahp = Ahi + (size_t)(bm*128 + ar) * lda + ao*8;
    const unsigned short* Alp = Alo + (size_t)(bm*128 + ar) * lda + ao*8;
    // precomputed LDS staging indices (A)
    const int aidx0 = (((ao    >>1)*4 + (ar>>5))*64 + (ar & 31) + 32*( ao     & 1)) * 8;
    const int aidx1 = ((((ao+1)>>1)*4 + (ar>>5))*64 + (ar & 31) + 32*((ao+1) & 1)) * 8;
    // B staging ownership
    const int nn = tid % NT, kg = tid / NT;
    const float* Bptr = Bw + (size_t)(kg*KPT) * ldb + bn*NT + nn;

    uint4 pah0, pah1, pal0, pal1;
    float pb[KPT];

    // prologue: load tile k0=0
    pah0 = *(const uint4*)(Ahp);
    pah1 = *(const uint4*)(Ahp + 8);
    pal0 = *(const uint4*)(Alp);
    pal1 = *(const uint4*)(Alp + 8);
    #pragma unroll
    for (int j = 0; j < KPT; ++j) pb[j] = Bptr[(size_t)j * ldb];

    for (int k0 = 0; k0 < K; k0 += 32) {
        // ---- stage prefetched regs -> LDS
        *(uint4*)&Ah[aidx0] = pah0;
        *(uint4*)&Ah[aidx1] = pah1;
        *(uint4*)&Al[aidx0] = pal0;
        *(uint4*)&Al[aidx1] = pal1;
        #pragma unroll
        for (int c = 0; c < KPT/8; ++c) {
            unsigned int hw[4], lw[4];
            #pragma unroll
            for (int p = 0; p < 4; ++p) {
                unsigned short h0, l0, h1, l1;
                split2(pb[c*8 + 2*p],     h0, l0);
                split2(pb[c*8 + 2*p + 1], h1, l1);
                hw[p] = (unsigned int)h0 | ((unsigned int)h1 << 16);
                lw[p] = (unsigned int)l0 | ((unsigned int)l1 << 16);
            }
            const int k    = kg*KPT + c*8;
            const int base = (((k>>4)*BFRAG + (nn>>5))*64 + (nn & 31) + 32*((k>>3)&1))*8;
            *(uint4*)&Bh[base] = make_uint4(hw[0], hw[1], hw[2], hw[3]);
            *(uint4*)&Bl[base] = make_uint4(lw[0], lw[1], lw[2], lw[3]);
        }
        __syncthreads();                  // staging visible

        // ---- issue next-tile global loads (unconditional; wraps to 0 at end)
        const int kn = (k0 + 32 < K) ? (k0 + 32) : 0;
        pah0 = *(const uint4*)(Ahp + kn);
        pah1 = *(const uint4*)(Ahp + kn + 8);
        pal0 = *(const uint4*)(Alp + kn);
        pal1 = *(const uint4*)(Alp + kn + 8);
        #pragma unroll
        for (int j = 0; j < KPT; ++j) pb[j] = Bptr[(size_t)(kn + j) * ldb];

        // ---- MFMA phase over staged LDS
        #pragma unroll
        for (int ks = 0; ks < 2; ++ks) {
            bf16x8 ah[2], al2[2], bh2[NF], bl2[NF];
            #pragma unroll
            for (int mf = 0; mf < 2; ++mf) {
                const int idx = ((ks*4 + wr*2 + mf)*64 + lane) * 8;
                ah[mf]  = *(const bf16x8*)&Ah[idx];
                al2[mf] = *(const bf16x8*)&Al[idx];
            }
            #pragma unroll
            for (int nf = 0; nf < NF; ++nf) {
                const int idx = ((ks*BFRAG + wc*NF + nf)*64 + lane) * 8;
                bh2[nf] = *(const bf16x8*)&Bh[idx];
                bl2[nf] = *(const bf16x8*)&Bl[idx];
            }
            #pragma unroll
            for (int mf = 0; mf < 2; ++mf)
                #pragma unroll
                for (int nf = 0; nf < NF; ++nf) {
                    acc[mf][nf] = __builtin_amdgcn_mfma_f32_32x32x16_bf16(ah[mf],  bh2[nf], acc[mf][nf], 0, 0, 0);
                    acc[mf][nf] = __builtin_amdgcn_mfma_f32_32x32x16_bf16(ah[mf],  bl2[nf], acc[mf][nf], 0, 0, 0);
                    acc[mf][nf] = __builtin_amdgcn_mfma_f32_32x32x16_bf16(al2[mf], bh2[nf], acc[mf][nf], 0, 0, 0);
                }
        }
        __syncthreads();                  // LDS reads done before next staging
    }

    // ---- epilogue. C/D layout: col=lane&31, row=4*(lane>>5)+(r&3)+8*(r>>2)
    #pragma unroll
    for (int mf = 0; mf < 2; ++mf)
        #pragma unroll
        for (int nf = 0; nf < NF; ++nf) {
            const int gcol = blockIdx.x*NT + wc*(32*NF) + nf*32 + lr;
            const float bsv = bias[bn*NT + wc*(32*NF) + nf*32 + lr];
            #pragma unroll
            for (int r = 0; r < 16; ++r) {
                const int grow = bm*128 + wr*64 + mf*32 + kb*4 + (r & 3) + 8*(r >> 2);
                float o = (acc[mf][nf][r] + bsv) * scale;
                if (HAS_RES) o += res[(size_t)grow * ldc + gcol];
                if (LEAKY)   o = o > 0.f ? o : 0.2f * o;
                if (OUTP) {
                    unsigned short h, l;
                    split2(o, h, l);
                    Chi[(size_t)grow * ldc + gcol] = h;
                    Clo[(size_t)grow * ldc + gcol] = l;
                } else {
                    Cf[(size_t)grow * ldc + gcol] = o;
                }
            }
        }
}

// ---------------------------------------------------------------- Attention
// grid (S/64, H+1, B); 256 threads. Flash-style over 8 key tiles of 64.
// q/k/v in fused qkv buffer [M][3072]. Output written as bf16 hi/lo planes.
__global__ __launch_bounds__(256)
void attn_kernel(const float* __restrict__ qkv, const float* __restrict__ mask,
                 const float* __restrict__ sattn, const float* __restrict__ sval,
                 unsigned short* __restrict__ combh, unsigned short* __restrict__ combl)
{
    __shared__ float QsT[64][64];   // [d][i]
    __shared__ float KT [64][64];   // [d][j]  (reused as PsT[j][i])
    __shared__ float Vs [64][64];   // [j][d]
    const int tid = threadIdx.x;
    const int tx = tid & 15, ty = tid >> 4;
    const int qt = blockIdx.x, hh = blockIdx.y, b = blockIdx.z;
    const bool special = (hh == HH);

    const int li  = tid >> 2;          // 0..63
    const int ld0 = (tid & 3) * 16;    // 0,16,32,48

    if (!special) {
        const float* qbase = qkv + ((size_t)(b*SS + qt*64 + li)) * QKV_LD + hh*DHH;
        #pragma unroll
        for (int u = 0; u < 4; u++) {
            float4 t = *(const float4*)(qbase + ld0 + u*4);
            QsT[ld0+u*4+0][li] = t.x; QsT[ld0+u*4+1][li] = t.y;
            QsT[ld0+u*4+2][li] = t.z; QsT[ld0+u*4+3][li] = t.w;
        }
    }

    float m_i[4], l_i[4], oacc[4][4];
    #pragma unroll
    for (int r = 0; r < 4; r++) {
        m_i[r] = -FLT_MAX_;
        l_i[r] = special ? 1.f : 0.f;
        #pragma unroll
        for (int c = 0; c < 4; c++) oacc[r][c] = 0.f;
    }

    for (int kt = 0; kt < 8; ++kt) {
        __syncthreads();   // previous PV reads done
        if (!special) {
            const float* kbase = qkv + ((size_t)(b*SS + kt*64 + li)) * QKV_LD + HD + hh*DHH;
            #pragma unroll
            for (int u = 0; u < 4; u++) {
                float4 t = *(const float4*)(kbase + ld0 + u*4);
                KT[ld0+u*4+0][li] = t.x; KT[ld0+u*4+1][li] = t.y;
                KT[ld0+u*4+2][li] = t.z; KT[ld0+u*4+3][li] = t.w;
            }
        } else {
            const float* pbase = sattn + ((size_t)b*SS + qt*64 + li) * SS + kt*64;
            #pragma unroll
            for (int u = 0; u < 4; u++) {
                float4 t = *(const float4*)(pbase + ld0 + u*4);
                KT[ld0+u*4+0][li] = t.x; KT[ld0+u*4+1][li] = t.y;
                KT[ld0+u*4+2][li] = t.z; KT[ld0+u*4+3][li] = t.w;
            }
        }
        {
            const float* vbase = (hh == 0)
                ? (sval + ((size_t)b*SS + kt*64 + li) * DHH)
                : (qkv + ((size_t)(b*SS + kt*64 + li)) * QKV_LD + 2*HD + (hh-1)*DHH);
            #pragma unroll
            for (int u = 0; u < 4; u++) {
                float4 t = *(const float4*)(vbase + ld0 + u*4);
                *(float4*)&Vs[li][ld0 + u*4] = t;
            }
        }
        __syncthreads();

        if (!special) {
            float sc[4][4];
            #pragma unroll
            for (int r = 0; r < 4; r++)
                #pragma unroll
                for (int c = 0; c < 4; c++) sc[r][c] = 0.f;
            #pragma unroll 8
            for (int d = 0; d < 64; ++d) {
                float4 qa = *(const float4*)&QsT[d][ty*4];
                float4 kb = *(const float4*)&KT[d][tx*4];
                float av[4] = {qa.x, qa.y, qa.z, qa.w};
                float bv[4] = {kb.x, kb.y, kb.z, kb.w};
                #pragma unroll
                for (int r = 0; r < 4; r++)
                    #pragma unroll
                    for (int c = 0; c < 4; c++)
                        sc[r][c] = fmaf(av[r], bv[c], sc[r][c]);
            }
            #pragma unroll
            for (int c = 0; c < 4; c++) {
                const float mk = mask[b*SS + kt*64 + tx*4 + c];
                const float add = (1.0f - mk) * NEG_MIN;
                #pragma unroll
                for (int r = 0; r < 4; r++)
                    sc[r][c] = sc[r][c] * mk + add;
            }
            float p[4][4];
            #pragma unroll
            for (int r = 0; r < 4; r++) {
                float rm = fmaxf(fmaxf(sc[r][0], sc[r][1]), fmaxf(sc[r][2], sc[r][3]));
                #pragma unroll
                for (int off = 1; off < 16; off <<= 1)
                    rm = fmaxf(rm, __shfl_xor(rm, off));
                const float m_new = fmaxf(m_i[r], rm);
                const float corr  = __expf(m_i[r] - m_new);
                float rs = 0.f;
                #pragma unroll
                for (int c = 0; c < 4; c++) {
                    p[r][c] = __expf(sc[r][c] - m_new);
                    rs += p[r][c];
                }
                #pragma unroll
                for (int off = 1; off < 16; off <<= 1)
                    rs += __shfl_xor(rs, off);
                l_i[r] = l_i[r] * corr + rs;
                m_i[r] = m_new;
                #pragma unroll
                for (int c = 0; c < 4; c++) oacc[r][c] *= corr;
            }
            __syncthreads();   // done reading KT
            #pragma unroll
            for (int r = 0; r < 4; r++)
                #pragma unroll
                for (int c = 0; c < 4; c++)
                    KT[tx*4+c][ty*4+r] = p[r][c];   // PsT[j][i]
            __syncthreads();   // PsT ready
        }
        #pragma unroll 8
        for (int j = 0; j < 64; ++j) {
            float4 pa = *(const float4*)&KT[j][ty*4];
            float4 vb = *(const float4*)&Vs[j][tx*4];
            float av[4] = {pa.x, pa.y, pa.z, pa.w};
            float bv[4] = {vb.x, vb.y, vb.z, vb.w};
            #pragma unroll
            for (int r = 0; r < 4; r++)
                #pragma unroll
                for (int c = 0; c < 4; c++)
                    oacc[r][c] = fmaf(av[r], bv[c], oacc[r][c]);
        }
    }
    #pragma unroll
    for (int r = 0; r < 4; r++) {
        const size_t row = (size_t)(b*SS + qt*64 + ty*4 + r);
        const float invl = 1.0f / l_i[r];
        ushort4 h4, l4;
        split2(oacc[r][0]*invl, h4.x, l4.x);
        split2(oacc[r][1]*invl, h4.y, l4.y);
        split2(oacc[r][2]*invl, h4.z, l4.z);
        split2(oacc[r][3]*invl, h4.w, l4.w);
        *(ushort4*)&combh[row * CD + hh*DHH + tx*4] = h4;
        *(ushort4*)&combl[row * CD + hh*DHH + tx*4] = l4;
    }
}

// ---------------------------------------------------------------- launch
extern "C" void kernel_launch(void* const* d_in, const int* in_sizes, int n_in,
                              void* d_out, int out_size, void* d_ws, size_t ws_size,
                              hipStream_t stream)
{
    const float* x     = (const float*)d_in[0];
    const float* mask  = (const float*)d_in[1];
    const float* sattn = (const float*)d_in[2];
    const float* sval  = (const float*)d_in[3];
    const float* Wq    = (const float*)d_in[4];
    const float* bq    = (const float*)d_in[5];
    const float* Wk    = (const float*)d_in[6];
    const float* bk    = (const float*)d_in[7];
    const float* Wv    = (const float*)d_in[8];
    const float* bv    = (const float*)d_in[9];
    const float* Wo    = (const float*)d_in[10];
    const float* bo    = (const float*)d_in[11];
    const float* ln1g  = (const float*)d_in[12];
    const float* ln1b  = (const float*)d_in[13];
    const float* W1    = (const float*)d_in[14];
    const float* b1    = (const float*)d_in[15];
    const float* W2    = (const float*)d_in[16];
    const float* b2    = (const float*)d_in[17];
    const float* ln2g  = (const float*)d_in[18];
    const float* ln2b  = (const float*)d_in[19];

    // ws layout (bytes) — identical extent to the validated runs.
    char* wsb = (char*)d_ws;
    unsigned short* yh    = (unsigned short*)(wsb);               //  8,388,608
    unsigned short* yl    = (unsigned short*)(wsb + 8388608);     //  8,388,608
    float*          qkv   = (float*)         (wsb + 16777216);    // 50,331,648
    unsigned short* hhp   = (unsigned short*)(wsb);               // 33,554,432 (aliases y+qkv, dead)
    unsigned short* hlp   = (unsigned short*)(wsb + 33554432);    // 33,554,432 (ends 67,108,864)
    unsigned short* combh = (unsigned short*)(wsb + 67108864);    //  8,912,896
    unsigned short* combl = (unsigned short*)(wsb + 76021760);    //  8,912,896
    float*          x2    = (float*)         (wsb + 84934656);    // 16,777,216
    unsigned short* y2h   = (unsigned short*)(wsb + 101711872);   //  8,388,608
    unsigned short* y2l   = (unsigned short*)(wsb + 110100480);   //  8,388,608

    const dim3 blk(256);

    ln_plane_kernel<<<MM, blk, 0, stream>>>(x, ln1g, ln1b, yh, yl);

    gemm_mfma<true,false,false,false,128><<<dim3(24, 32), blk, 0, stream>>>(
        yh, yl, Wq, Wk, Wv, bq, bk, bv,
        nullptr, qkv, nullptr, nullptr, DD, DD, DD, QKV_LD);

    attn_kernel<<<dim3(SS/64, HH+1, BB), blk, 0, stream>>>(qkv, mask, sattn, sval, combh, combl);

    gemm_mfma<false,true,false,false,64><<<dim3(16, 32), blk, 0, stream>>>(
        combh, combl, Wo, nullptr, nullptr, bo, nullptr, nullptr,
        x, x2, nullptr, nullptr, CD, CD, DD, DD);

    ln_plane_kernel<<<MM, blk, 0, stream>>>(x2, ln2g, ln2b, y2h, y2l);

    gemm_mfma<false,false,true,true,128><<<dim3(32, 32), blk, 0, stream>>>(
        y2h, y2l, W1, nullptr, nullptr, b1, nullptr, nullptr,
        nullptr, nullptr, hhp, hlp, DD, DD, FFF, FFF);

    gemm_mfma<false,true,false,false,64><<<dim3(16, 32), blk, 0, stream>>>(
        hhp, hlp, W2, nullptr, nullptr, b2, nullptr, nullptr,
        x2, (float*)d_out, nullptr, nullptr, FFF, FFF, DD, DD);
}

// Round 8
// 614.737 us; speedup vs baseline: 1.9448x; 1.2249x over previous
//
#include <hip/hip_runtime.h>
#include <hip/hip_bf16.h>

#define BB 8
#define SS 512
#define DD 1024
#define HH 16
#define DHH 64
#define FFF 4096
#define MM (BB*SS)        // 4096
#define HD (HH*DHH)       // 1024
#define CD ((HH+1)*DHH)   // 1088
#define QKV_LD 3072

#define NEG_MIN (-3.4028234663852886e38f)
#define FLT_MAX_ (3.402823466e+38f)

typedef __attribute__((ext_vector_type(8)))  __bf16 bf16x8;
typedef __attribute__((ext_vector_type(16))) float  f32x16;

__device__ __forceinline__ unsigned short bf16_rne(float x) {
    unsigned int u = __float_as_uint(x);
    u += 0x7FFFu + ((u >> 16) & 1u);
    return (unsigned short)(u >> 16);
}
__device__ __forceinline__ float bf16f(unsigned short h) {
    return __uint_as_float(((unsigned int)h) << 16);
}
__device__ __forceinline__ void split2(float x, unsigned short& h, unsigned short& l) {
    h = bf16_rne(x);
    l = bf16_rne(x - bf16f(h));
}

// ------------------------------------------------- LayerNorm -> hi/lo planes
__global__ __launch_bounds__(256)
void ln_plane_kernel(const float* __restrict__ x, const float* __restrict__ g,
                     const float* __restrict__ bta,
                     unsigned short* __restrict__ oh, unsigned short* __restrict__ ol)
{
    const int row = blockIdx.x;
    const int tid = threadIdx.x;
    const float* xr = x + (size_t)row * DD;
    float4 xv = *(const float4*)(xr + tid * 4);
    float s  = xv.x + xv.y + xv.z + xv.w;
    float ss = xv.x*xv.x + xv.y*xv.y + xv.z*xv.z + xv.w*xv.w;
    #pragma unroll
    for (int off = 32; off > 0; off >>= 1) {
        s  += __shfl_down(s, off);
        ss += __shfl_down(ss, off);
    }
    __shared__ float red[8];
    const int wid = tid >> 6;
    if ((tid & 63) == 0) { red[wid*2] = s; red[wid*2+1] = ss; }
    __syncthreads();
    s  = red[0] + red[2] + red[4] + red[6];
    ss = red[1] + red[3] + red[5] + red[7];
    const float mu  = s * (1.0f / DD);
    const float var = ss * (1.0f / DD) - mu * mu;
    const float inv = 1.0f / sqrtf(var + 1e-6f);
    float4 gv = *(const float4*)(g + tid*4);
    float4 bv = *(const float4*)(bta + tid*4);
    float o0 = (xv.x - mu) * inv * gv.x + bv.x;
    float o1 = (xv.y - mu) * inv * gv.y + bv.y;
    float o2 = (xv.z - mu) * inv * gv.z + bv.z;
    float o3 = (xv.w - mu) * inv * gv.w + bv.w;
    ushort4 h4, l4;
    split2(o0, h4.x, l4.x); split2(o1, h4.y, l4.y);
    split2(o2, h4.z, l4.z); split2(o3, h4.w, l4.w);
    *(ushort4*)&oh[(size_t)row * DD + tid*4] = h4;
    *(ushort4*)&ol[(size_t)row * DD + tid*4] = l4;
}

// ---------------------------------------------------------------- MFMA GEMM
// (unchanged from the validated 753us build)
template<bool QKV, bool HAS_RES, bool LEAKY, bool OUTP, int NT>
__global__ __launch_bounds__(256)
void gemm_mfma(const unsigned short* __restrict__ Ahi,
               const unsigned short* __restrict__ Alo,
               const float* __restrict__ B0, const float* __restrict__ B1,
               const float* __restrict__ B2,
               const float* __restrict__ bias0, const float* __restrict__ bias1,
               const float* __restrict__ bias2,
               const float* __restrict__ res, float* __restrict__ Cf,
               unsigned short* __restrict__ Chi, unsigned short* __restrict__ Clo,
               int K, int lda, int ldb, int ldc)
{
    static_assert(NT == 64 || NT == 128, "");
    constexpr int NF    = NT / 64;
    constexpr int BFRAG = NT / 32;
    constexpr int KG    = 256 / NT;
    constexpr int KPT   = 32 / KG;

    __shared__ unsigned short Ah[4096];
    __shared__ unsigned short Al[4096];
    __shared__ unsigned short Bh[BFRAG * 2 * 64 * 8];
    __shared__ unsigned short Bl[BFRAG * 2 * 64 * 8];

    const int tid = threadIdx.x;
    const int bm  = blockIdx.y;
    int bn = blockIdx.x;

    const float* Bw   = B0;
    const float* bias = bias0;
    float scale = 1.0f;
    if (QKV) {
        const int sel = bn >> 3;
        Bw   = (sel == 0) ? B0 : (sel == 1 ? B1 : B2);
        bias = (sel == 0) ? bias0 : (sel == 1 ? bias1 : bias2);
        scale = (sel == 0) ? 0.125f : 1.0f;
        bn &= 7;
    }

    const int wid  = tid >> 6, lane = tid & 63;
    const int wr   = wid >> 1, wc = wid & 1;
    const int lr   = lane & 31, kb = lane >> 5;

    f32x16 acc[2][NF];
    #pragma unroll
    for (int i = 0; i < 2; i++)
        #pragma unroll
        for (int j = 0; j < NF; j++)
            #pragma unroll
            for (int r = 0; r < 16; r++) acc[i][j][r] = 0.f;

    const int ar = tid >> 1, ao = (tid & 1) * 2;
    const unsigned short* Ahp = Ahi + (size_t)(bm*128 + ar) * lda + ao*8;
    const unsigned short* Alp = Alo + (size_t)(bm*128 + ar) * lda + ao*8;
    const int aidx0 = (((ao    >>1)*4 + (ar>>5))*64 + (ar & 31) + 32*( ao     & 1)) * 8;
    const int aidx1 = ((((ao+1)>>1)*4 + (ar>>5))*64 + (ar & 31) + 32*((ao+1) & 1)) * 8;
    const int nn = tid % NT, kg = tid / NT;
    const float* Bptr = Bw + (size_t)(kg*KPT) * ldb + bn*NT + nn;

    uint4 pah0, pah1, pal0, pal1;
    float pb[KPT];

    pah0 = *(const uint4*)(Ahp);
    pah1 = *(const uint4*)(Ahp + 8);
    pal0 = *(const uint4*)(Alp);
    pal1 = *(const uint4*)(Alp + 8);
    #pragma unroll
    for (int j = 0; j < KPT; ++j) pb[j] = Bptr[(size_t)j * ldb];

    for (int k0 = 0; k0 < K; k0 += 32) {
        *(uint4*)&Ah[aidx0] = pah0;
        *(uint4*)&Ah[aidx1] = pah1;
        *(uint4*)&Al[aidx0] = pal0;
        *(uint4*)&Al[aidx1] = pal1;
        #pragma unroll
        for (int c = 0; c < KPT/8; ++c) {
            unsigned int hw[4], lw[4];
            #pragma unroll
            for (int p = 0; p < 4; ++p) {
                unsigned short h0, l0, h1, l1;
                split2(pb[c*8 + 2*p],     h0, l0);
                split2(pb[c*8 + 2*p + 1], h1, l1);
                hw[p] = (unsigned int)h0 | ((unsigned int)h1 << 16);
                lw[p] = (unsigned int)l0 | ((unsigned int)l1 << 16);
            }
            const int k    = kg*KPT + c*8;
            const int base = (((k>>4)*BFRAG + (nn>>5))*64 + (nn & 31) + 32*((k>>3)&1))*8;
            *(uint4*)&Bh[base] = make_uint4(hw[0], hw[1], hw[2], hw[3]);
            *(uint4*)&Bl[base] = make_uint4(lw[0], lw[1], lw[2], lw[3]);
        }
        __syncthreads();

        const int kn = (k0 + 32 < K) ? (k0 + 32) : 0;
        pah0 = *(const uint4*)(Ahp + kn);
        pah1 = *(const uint4*)(Ahp + kn + 8);
        pal0 = *(const uint4*)(Alp + kn);
        pal1 = *(const uint4*)(Alp + kn + 8);
        #pragma unroll
        for (int j = 0; j < KPT; ++j) pb[j] = Bptr[(size_t)(kn + j) * ldb];

        #pragma unroll
        for (int ks = 0; ks < 2; ++ks) {
            bf16x8 ah[2], al2[2], bh2[NF], bl2[NF];
            #pragma unroll
            for (int mf = 0; mf < 2; ++mf) {
                const int idx = ((ks*4 + wr*2 + mf)*64 + lane) * 8;
                ah[mf]  = *(const bf16x8*)&Ah[idx];
                al2[mf] = *(const bf16x8*)&Al[idx];
            }
            #pragma unroll
            for (int nf = 0; nf < NF; ++nf) {
                const int idx = ((ks*BFRAG + wc*NF + nf)*64 + lane) * 8;
                bh2[nf] = *(const bf16x8*)&Bh[idx];
                bl2[nf] = *(const bf16x8*)&Bl[idx];
            }
            #pragma unroll
            for (int mf = 0; mf < 2; ++mf)
                #pragma unroll
                for (int nf = 0; nf < NF; ++nf) {
                    acc[mf][nf] = __builtin_amdgcn_mfma_f32_32x32x16_bf16(ah[mf],  bh2[nf], acc[mf][nf], 0, 0, 0);
                    acc[mf][nf] = __builtin_amdgcn_mfma_f32_32x32x16_bf16(ah[mf],  bl2[nf], acc[mf][nf], 0, 0, 0);
                    acc[mf][nf] = __builtin_amdgcn_mfma_f32_32x32x16_bf16(al2[mf], bh2[nf], acc[mf][nf], 0, 0, 0);
                }
        }
        __syncthreads();
    }

    #pragma unroll
    for (int mf = 0; mf < 2; ++mf)
        #pragma unroll
        for (int nf = 0; nf < NF; ++nf) {
            const int gcol = blockIdx.x*NT + wc*(32*NF) + nf*32 + lr;
            const float bsv = bias[bn*NT + wc*(32*NF) + nf*32 + lr];
            #pragma unroll
            for (int r = 0; r < 16; ++r) {
                const int grow = bm*128 + wr*64 + mf*32 + kb*4 + (r & 3) + 8*(r >> 2);
                float o = (acc[mf][nf][r] + bsv) * scale;
                if (HAS_RES) o += res[(size_t)grow * ldc + gcol];
                if (LEAKY)   o = o > 0.f ? o : 0.2f * o;
                if (OUTP) {
                    unsigned short h, l;
                    split2(o, h, l);
                    Chi[(size_t)grow * ldc + gcol] = h;
                    Clo[(size_t)grow * ldc + gcol] = l;
                } else {
                    Cf[(size_t)grow * ldc + gcol] = o;
                }
            }
        }
}

// ---------------------------------------------------------------- MFMA Attention
// grid (SS/128, HH+1, BB); 256 thr = 4 waves, each wave owns 32 q-rows.
// Swapped QK^T (S^T = K·Q^T) so each lane holds one q-row -> in-register
// softmax (31 max + 1 shfl_xor(32)). Q split-bf16 in REGISTERS (B-frags).
// K split-bf16 (3-MFMA scores); V split-bf16, P plain bf16 (2-MFMA PV),
// PV computed as O^T = V^T·P^T. All LDS frag units XOR-swizzled
// (u ^= (u>>3)&7, involution, applied to write & read) to spread staging
// banks; frag reads are linear b128 like the validated GEMM.
// KP buffer unions K(hi/lo) with P frags. Special head (hh==16): P staged
// straight from sattn (de-swizzled source), no softmax, l=1.
__global__ __launch_bounds__(256)
void attn_mfma(const float* __restrict__ qkv, const float* __restrict__ mask,
               const float* __restrict__ sattn, const float* __restrict__ sval,
               unsigned short* __restrict__ combh, unsigned short* __restrict__ combl)
{
    __shared__ unsigned short KP[8192];   // K: hi[0:4096) lo[4096:8192)  |  P frags
    __shared__ unsigned short Vh[4096], Vl[4096];
    __shared__ float msk[SS];

    const int tid = threadIdx.x;
    const int w = tid >> 6, l = tid & 63, q = l & 31, lh = l >> 5;
    const int qt = blockIdx.x, hh = blockIdx.y, b = blockIdx.z;
    const bool special = (hh == HH);
    const int swzl = l ^ ((l >> 3) & 7);

    msk[tid]       = mask[b*SS + tid];
    msk[tid + 256] = mask[b*SS + tid + 256];

    union U8 { bf16x8 v; unsigned short s[8]; };

    // Q fragments in registers (B-operand: lane=col q, k-half = lh)
    bf16x8 qfh[4], qfl[4];
    if (!special) {
        const float* qp = qkv + ((size_t)(b*SS + qt*128 + w*32 + q))*QKV_LD + hh*DHH + lh*8;
        #pragma unroll
        for (int ks = 0; ks < 4; ++ks) {
            float4 a  = *(const float4*)(qp + ks*16);
            float4 c2 = *(const float4*)(qp + ks*16 + 4);
            U8 Hf, Lf;
            split2(a.x,  Hf.s[0], Lf.s[0]); split2(a.y,  Hf.s[1], Lf.s[1]);
            split2(a.z,  Hf.s[2], Lf.s[2]); split2(a.w,  Hf.s[3], Lf.s[3]);
            split2(c2.x, Hf.s[4], Lf.s[4]); split2(c2.y, Hf.s[5], Lf.s[5]);
            split2(c2.z, Hf.s[6], Lf.s[6]); split2(c2.w, Hf.s[7], Lf.s[7]);
            qfh[ks] = Hf.v; qfl[ks] = Lf.v;
        }
    }

    f32x16 ot0, ot1;
    #pragma unroll
    for (int r = 0; r < 16; ++r) { ot0[r] = 0.f; ot1[r] = 0.f; }
    float m_i  = -FLT_MAX_;
    float l_acc = special ? 1.f : 0.f;

    const int skey = tid >> 2;          // staging: key 0..63
    const int sd0  = (tid & 3) * 16;    // staging: d-chunk

    for (int kt = 0; kt < 8; ++kt) {
        __syncthreads();                // prev PV done reading KP/V

        // ---- stage V (transposed frags, hi/lo)
        {
            const float* vrow = (hh == 0)
                ? (sval + ((size_t)(b*SS + kt*64 + skey))*DHH + sd0)
                : (qkv + ((size_t)(b*SS + kt*64 + skey))*QKV_LD + 2*HD + (hh-1)*DHH + sd0);
            #pragma unroll
            for (int c = 0; c < 4; ++c) {
                float4 t4 = *(const float4*)(vrow + c*4);
                float vv[4] = {t4.x, t4.y, t4.z, t4.w};
                #pragma unroll
                for (int j2 = 0; j2 < 4; ++j2) {
                    const int d = sd0 + c*4 + j2;
                    unsigned short hsv, lsv; split2(vv[j2], hsv, lsv);
                    const int ur   = (d & 31) + 32*((skey >> 3) & 1);
                    const int unit = ((d >> 5)*4 + (skey >> 4))*64 + (ur ^ ((ur >> 3) & 7));
                    Vh[unit*8 + (skey & 7)] = hsv;
                    Vl[unit*8 + (skey & 7)] = lsv;
                }
            }
        }
        if (!special) {
            // ---- stage K (A-operand frags, hi/lo, packed u32 pairs)
            const float* krow = qkv + ((size_t)(b*SS + kt*64 + skey))*QKV_LD + HD + hh*DHH + sd0;
            #pragma unroll
            for (int c = 0; c < 4; ++c) {
                float4 t4 = *(const float4*)(krow + c*4);
                unsigned short hs[4], ls[4];
                split2(t4.x, hs[0], ls[0]); split2(t4.y, hs[1], ls[1]);
                split2(t4.z, hs[2], ls[2]); split2(t4.w, hs[3], ls[3]);
                #pragma unroll
                for (int pp = 0; pp < 2; ++pp) {
                    const int d = sd0 + c*4 + pp*2;
                    const unsigned int ph = (unsigned int)hs[pp*2] | ((unsigned int)hs[pp*2+1] << 16);
                    const unsigned int pl = (unsigned int)ls[pp*2] | ((unsigned int)ls[pp*2+1] << 16);
                    const int ur   = (skey & 31) + 32*((d >> 3) & 1);
                    const int unit = ((skey >> 5)*4 + (d >> 4))*64 + (ur ^ ((ur >> 3) & 7));
                    *(unsigned int*)&KP[unit*8 + (d & 7)]        = ph;
                    *(unsigned int*)&KP[4096 + unit*8 + (d & 7)] = pl;
                }
            }
        } else {
            // ---- stage P straight from sattn (plain bf16 B-frags)
            #pragma unroll
            for (int i2 = 0; i2 < 4; ++i2) {
                const int ug = i2*256 + tid;              // stored unit 0..1023
                const int wq = ug >> 8, ks = (ug >> 6) & 3, usw = ug & 63;
                const int lr2 = usw ^ ((usw >> 3) & 7);   // involution -> (q,kh)
                const int qq = lr2 & 31, kh = lr2 >> 5;
                const float* pp = sattn + ((size_t)(b*SS + qt*128 + wq*32 + qq))*SS
                                + kt*64 + ks*16 + kh*8;
                float4 a  = *(const float4*)pp;
                float4 c2 = *(const float4*)(pp + 4);
                U8 P8;
                P8.s[0]=bf16_rne(a.x);  P8.s[1]=bf16_rne(a.y);
                P8.s[2]=bf16_rne(a.z);  P8.s[3]=bf16_rne(a.w);
                P8.s[4]=bf16_rne(c2.x); P8.s[5]=bf16_rne(c2.y);
                P8.s[6]=bf16_rne(c2.z); P8.s[7]=bf16_rne(c2.w);
                *(bf16x8*)&KP[ug*8] = P8.v;
            }
        }
        __syncthreads();

        if (!special) {
            // ---- S^T = K · Q^T (split-bf16, 3 MFMA per product)
            f32x16 st0, st1;
            #pragma unroll
            for (int r = 0; r < 16; ++r) { st0[r] = 0.f; st1[r] = 0.f; }
            #pragma unroll
            for (int ks = 0; ks < 4; ++ks) {
                bf16x8 k0h = *(const bf16x8*)&KP[((    ks)*64 + swzl)*8];
                bf16x8 k0l = *(const bf16x8*)&KP[4096 + ((    ks)*64 + swzl)*8];
                bf16x8 k1h = *(const bf16x8*)&KP[((4 + ks)*64 + swzl)*8];
                bf16x8 k1l = *(const bf16x8*)&KP[4096 + ((4 + ks)*64 + swzl)*8];
                st0 = __builtin_amdgcn_mfma_f32_32x32x16_bf16(k0h, qfh[ks], st0, 0, 0, 0);
                st0 = __builtin_amdgcn_mfma_f32_32x32x16_bf16(k0h, qfl[ks], st0, 0, 0, 0);
                st0 = __builtin_amdgcn_mfma_f32_32x32x16_bf16(k0l, qfh[ks], st0, 0, 0, 0);
                st1 = __builtin_amdgcn_mfma_f32_32x32x16_bf16(k1h, qfh[ks], st1, 0, 0, 0);
                st1 = __builtin_amdgcn_mfma_f32_32x32x16_bf16(k1h, qfl[ks], st1, 0, 0, 0);
                st1 = __builtin_amdgcn_mfma_f32_32x32x16_bf16(k1l, qfh[ks], st1, 0, 0, 0);
            }
            // ---- mask + online softmax (lane = one q-row)
            float pmax = -FLT_MAX_;
            #pragma unroll
            for (int r = 0; r < 16; ++r) {
                const int kl0 = (r & 3) + 8*(r >> 2) + 4*lh;
                const float mv0 = msk[kt*64 + kl0];
                const float mv1 = msk[kt*64 + 32 + kl0];
                st0[r] = st0[r]*mv0 + (1.f - mv0)*NEG_MIN;
                st1[r] = st1[r]*mv1 + (1.f - mv1)*NEG_MIN;
                pmax = fmaxf(pmax, fmaxf(st0[r], st1[r]));
            }
            pmax = fmaxf(pmax, __shfl_xor(pmax, 32));
            const float m_new = fmaxf(m_i, pmax);
            const float corr  = __expf(m_i - m_new);
            float rs = 0.f;
            #pragma unroll
            for (int r = 0; r < 16; ++r) {
                st0[r] = __expf(st0[r] - m_new);
                st1[r] = __expf(st1[r] - m_new);
                rs += st0[r] + st1[r];
            }
            rs += __shfl_xor(rs, 32);
            l_acc = l_acc*corr + rs;
            m_i = m_new;
            #pragma unroll
            for (int r = 0; r < 16; ++r) { ot0[r] *= corr; ot1[r] *= corr; }

            __syncthreads();            // all waves done reading K
            // ---- write P bf16 B-frags (pair-packed u32)
            #pragma unroll
            for (int t2 = 0; t2 < 2; ++t2)
                #pragma unroll
                for (int rr = 0; rr < 16; rr += 2) {
                    const int Kk = t2*32 + (rr & 3) + 8*(rr >> 2) + 4*lh;
                    const int ks = Kk >> 4, kh = (Kk >> 3) & 1, e = Kk & 7;
                    const int ur = q + 32*kh;
                    const int unit = (w*4 + ks)*64 + (ur ^ ((ur >> 3) & 7));
                    const float p0 = t2 ? st1[rr]     : st0[rr];
                    const float p1 = t2 ? st1[rr + 1] : st0[rr + 1];
                    const unsigned int pk = (unsigned int)bf16_rne(p0)
                                          | ((unsigned int)bf16_rne(p1) << 16);
                    *(unsigned int*)&KP[unit*8 + e] = pk;
                }
            __syncthreads();            // P visible
        }

        // ---- PV: O^T += V^T · P^T (V split, P plain: 2 MFMA per product)
        #pragma unroll
        for (int ks = 0; ks < 4; ++ks) {
            bf16x8 pf  = *(const bf16x8*)&KP[((w*4 + ks)*64 + swzl)*8];
            bf16x8 v0h = *(const bf16x8*)&Vh[((    ks)*64 + swzl)*8];
            bf16x8 v0l = *(const bf16x8*)&Vl[((    ks)*64 + swzl)*8];
            bf16x8 v1h = *(const bf16x8*)&Vh[((4 + ks)*64 + swzl)*8];
            bf16x8 v1l = *(const bf16x8*)&Vl[((4 + ks)*64 + swzl)*8];
            ot0 = __builtin_amdgcn_mfma_f32_32x32x16_bf16(v0h, pf, ot0, 0, 0, 0);
            ot0 = __builtin_amdgcn_mfma_f32_32x32x16_bf16(v0l, pf, ot0, 0, 0, 0);
            ot1 = __builtin_amdgcn_mfma_f32_32x32x16_bf16(v1h, pf, ot1, 0, 0, 0);
            ot1 = __builtin_amdgcn_mfma_f32_32x32x16_bf16(v1l, pf, ot1, 0, 0, 0);
        }
    }

    // ---- epilogue: normalize + write comb hi/lo planes
    const float invl = 1.f / l_acc;
    const size_t row = (size_t)(b*SS + qt*128 + w*32 + q);
    #pragma unroll
    for (int dt = 0; dt < 2; ++dt)
        #pragma unroll
        for (int r = 0; r < 16; ++r) {
            const int d = dt*32 + (r & 3) + 8*(r >> 2) + 4*lh;
            const float v = (dt ? ot1[r] : ot0[r]) * invl;
            unsigned short hv, lv; split2(v, hv, lv);
            combh[row*CD + hh*DHH + d] = hv;
            combl[row*CD + hh*DHH + d] = lv;
        }
}

// ---------------------------------------------------------------- launch
extern "C" void kernel_launch(void* const* d_in, const int* in_sizes, int n_in,
                              void* d_out, int out_size, void* d_ws, size_t ws_size,
                              hipStream_t stream)
{
    const float* x     = (const float*)d_in[0];
    const float* mask  = (const float*)d_in[1];
    const float* sattn = (const float*)d_in[2];
    const float* sval  = (const float*)d_in[3];
    const float* Wq    = (const float*)d_in[4];
    const float* bq    = (const float*)d_in[5];
    const float* Wk    = (const float*)d_in[6];
    const float* bk    = (const float*)d_in[7];
    const float* Wv    = (const float*)d_in[8];
    const float* bv    = (const float*)d_in[9];
    const float* Wo    = (const float*)d_in[10];
    const float* bo    = (const float*)d_in[11];
    const float* ln1g  = (const float*)d_in[12];
    const float* ln1b  = (const float*)d_in[13];
    const float* W1    = (const float*)d_in[14];
    const float* b1    = (const float*)d_in[15];
    const float* W2    = (const float*)d_in[16];
    const float* b2    = (const float*)d_in[17];
    const float* ln2g  = (const float*)d_in[18];
    const float* ln2b  = (const float*)d_in[19];

    // ws layout (bytes) — identical extent to the validated runs.
    char* wsb = (char*)d_ws;
    unsigned short* yh    = (unsigned short*)(wsb);               //  8,388,608
    unsigned short* yl    = (unsigned short*)(wsb + 8388608);     //  8,388,608
    float*          qkv   = (float*)         (wsb + 16777216);    // 50,331,648
    unsigned short* hhp   = (unsigned short*)(wsb);               // 33,554,432 (aliases y+qkv, dead)
    unsigned short* hlp   = (unsigned short*)(wsb + 33554432);    // 33,554,432 (ends 67,108,864)
    unsigned short* combh = (unsigned short*)(wsb + 67108864);    //  8,912,896
    unsigned short* combl = (unsigned short*)(wsb + 76021760);    //  8,912,896
    float*          x2    = (float*)         (wsb + 84934656);    // 16,777,216
    unsigned short* y2h   = (unsigned short*)(wsb + 101711872);   //  8,388,608
    unsigned short* y2l   = (unsigned short*)(wsb + 110100480);   //  8,388,608

    const dim3 blk(256);

    ln_plane_kernel<<<MM, blk, 0, stream>>>(x, ln1g, ln1b, yh, yl);

    gemm_mfma<true,false,false,false,128><<<dim3(24, 32), blk, 0, stream>>>(
        yh, yl, Wq, Wk, Wv, bq, bk, bv,
        nullptr, qkv, nullptr, nullptr, DD, DD, DD, QKV_LD);

    attn_mfma<<<dim3(SS/128, HH+1, BB), blk, 0, stream>>>(qkv, mask, sattn, sval, combh, combl);

    gemm_mfma<false,true,false,false,64><<<dim3(16, 32), blk, 0, stream>>>(
        combh, combl, Wo, nullptr, nullptr, bo, nullptr, nullptr,
        x, x2, nullptr, nullptr, CD, CD, DD, DD);

    ln_plane_kernel<<<MM, blk, 0, stream>>>(x2, ln2g, ln2b, y2h, y2l);

    gemm_mfma<false,false,true,true,128><<<dim3(32, 32), blk, 0, stream>>>(
        y2h, y2l, W1, nullptr, nullptr, b1, nullptr, nullptr,
        nullptr, nullptr, hhp, hlp, DD, DD, FFF, FFF);

    gemm_mfma<false,true,false,false,64><<<dim3(16, 32), blk, 0, stream>>>(
        hhp, hlp, W2, nullptr, nullptr, b2, nullptr, nullptr,
        x2, (float*)d_out, nullptr, nullptr, FFF, FFF, DD, DD);
}